// Round 6
// baseline (263.134 us; speedup 1.0000x reference)
//
#include <hip/hip_runtime.h>

// out[b,c,y,x] = sum_{dy,dx in [0,13)} aff[b, dy*13+dx, y, x] * in2_zp[b, c, y+dy-6, x+dx-6]
// B=4 C=64 H=W=192 D=169.
//
// Round 12: r11 (141us) was still latency-serialized: VGPR=60 proves the
// compiler would not keep W[4][10] resident, so the pass degenerated into
// ds_read->dot2 dependency chains (~7800cy/iter vs ~600cy issue), and
// __syncthreads' vmcnt(0) drain killed aff-load coverage at every barrier.
// Fixes:
//  * W is now PINNED in regs (asm "+v"), pass split into two i-halves
//    (20 W regs each) to fit <=128 VGPR; batched W reads = one lgkm wait.
//  * aff A4 chunks manually double-buffered + pinned inside the m-loop.
//  * raw barrier "s_waitcnt lgkmcnt(0); s_barrier" (T4): LDS visibility
//    only needs lgkmcnt; aff global loads stay IN FLIGHT across barriers.
//  * aff reg-staging is depth-2: loads issued at iter rr (slice dy=rr+2),
//    packed+written at rr+1, consumed at rr+2 -> ~2 passes (~1600cy) cover
//    the ~900cy HBM latency. apk double buffer unchanged (writes depth-1).
//  * everything else (window layout pitch 42, Sv staging, grid (768,3)
//    XCD swizzle, dot2 core) identical to r11.
// Numerics: aff fp16 rtz + in2 fp16 rtz, fp32 accum (= r11, absmax .25-.5).

#define KD   6
#define WIN  13
#define ND   169
#define NB   4
#define NC   64
#define NH   192
#define NW   192
#define HW   (NH * NW)
#define XH   64            // x-tile width per block (3 tiles across W)
#define PITCHW 42          // window LDS row pitch in words (84 halves >= 80)
#define BUFW (NC * PITCHW) // 2688 words per window buffer
#define AFFPW 448          // 7*64 pair-words per packed aff slice
#define NTH  256           // 4 waves

typedef _Float16 half2v __attribute__((ext_vector_type(2)));

static __device__ __forceinline__ half2v h2(unsigned u) {
    return __builtin_bit_cast(half2v, u);
}
static __device__ __forceinline__ unsigned pk(float a, float b) {
    return __builtin_bit_cast(unsigned, __builtin_amdgcn_cvt_pkrtz(a, b));
}

#if __has_builtin(__builtin_amdgcn_fdot2)
#define FDOT2(a, b, c) __builtin_amdgcn_fdot2((a), (b), (c), false)
#else
static __device__ __forceinline__ float fdot2_fb(half2v a, half2v b, float c) {
    return fmaf((float)a.x, (float)b.x, fmaf((float)a.y, (float)b.y, c));
}
#define FDOT2(a, b, c) fdot2_fb((a), (b), (c))
#endif

// Raw barrier: LDS producer->consumer only needs lgkmcnt; do NOT drain
// vmcnt (keeps the depth-2 aff loads in flight across the barrier).
#define BARRIER() asm volatile("s_waitcnt lgkmcnt(0)\n\ts_barrier" ::: "memory")
#define PINF4(v) asm volatile("" : "+v"((v).x), "+v"((v).y), "+v"((v).z), "+v"((v).w))
#define PINU4(v) asm volatile("" : "+v"((v).x), "+v"((v).y), "+v"((v).z), "+v"((v).w))

__global__ __launch_bounds__(NTH)
__attribute__((amdgpu_waves_per_eu(4, 8)))
void mxassemble(const float* __restrict__ aff,
                const float* __restrict__ in2,
                float* __restrict__ out) {
    __shared__ unsigned ldsw[2 * BUFW];    // fp16 window rows, double buffered
    __shared__ unsigned apkw[2 * AFFPW];   // fp16 aff dx-pair slices, dbuf

    // Grid (768, 3): bx = (k<<3)|g. Per XCD g: k = b*24 + yl, yl fastest;
    // y = 24*g + yl -> each XCD owns a 24-row band per batch, rows L2-hot.
    const int bx = blockIdx.x;
    const int g  = bx & 7;
    const int k  = bx >> 3;                // 0..95
    const int b  = k / 24;
    const int yl = k - 24 * b;
    const int y  = 24 * g + yl;
    const int xb = blockIdx.y;             // x-tile 0..2
    const int X0 = xb * XH;

    const int t    = threadIdx.x;
    const int l    = t & 63;
    const int wv   = t >> 6;               // wave 0..3
    const int cg   = l & 15;               // channel group; c = cg + 16*i
    const int xs   = l >> 4;               // 0..3
    const int slot = wv * 4 + xs;          // 0..15
    const int x0   = X0 + slot * 4;

    // Window row layout: half j in [0,80) <-> global x = X0 - 8 + j.
    // Zero the 8-half OOB aprons once (xb=0: words 0..3; xb=2: words 36..39).
    if (xb != 1) {
        const int w0 = (xb == 0) ? 0 : 36;
        if (t < NC * 2) {
            const int c = t >> 1, qq = t & 1;
            *(uint2*)&ldsw[c * PITCHW + w0 + 2 * qq]        = make_uint2(0u, 0u);
            *(uint2*)&ldsw[BUFW + c * PITCHW + w0 + 2 * qq] = make_uint2(0u, 0u);
        }
    }

    // in2 staging slots: item s covers (c, q) = 4 floats; 64ch x 20 chunks
    // = 1280 = 256 threads x 5.
    int wadr[5], goff[5];
#pragma unroll
    for (int s = 0; s < 5; ++s) {
        const int ii = t + NTH * s;
        const int c  = ii / 20;
        const int q  = ii - 20 * c;
        const int xg = X0 - 8 + 4 * q;
        const bool ok = (xg >= 0) && (xg < NW);
        wadr[s] = ok ? (c * PITCHW + 2 * q) : -1;
        goff[s] = c * HW + xg;
    }

    // aff pair-staging mapping (t < 112): m = t>>4 in [0,7), xc = t&15.
    const int am  = t >> 4;
    const int axc = t & 15;
    const bool astg = (t < 112);
    const float* pA0 = aff + (size_t)b * ND * HW + (size_t)y * NW + X0
                           + 4 * axc + (size_t)(2 * am) * HW;
    const int aw = am * 64 + 4 * axc;

    float acc[4][4];
#pragma unroll
    for (int i = 0; i < 4; ++i)
#pragma unroll
        for (int j = 0; j < 4; ++j) acc[i][j] = 0.f;

    const float* in2_b = in2 + (size_t)b * NC * HW;
    const int wbase = cg * PITCHW + 2 * slot;

    // Depth-2 aff register pipeline: Ap = slice rr+1 (packed this iter),
    // An = slice rr+2 (loaded this iter).
    float4 Ap0 = make_float4(0.f, 0.f, 0.f, 0.f), Ap1 = Ap0;
    float4 An0 = Ap0, An1 = Ap0;

    // ---- prologue ----
    if (astg) {
        // slice dy=0 -> apk[0] immediately
        const float4 a0 = *(const float4*)pA0;
        float4 a1 = make_float4(0.f, 0.f, 0.f, 0.f);
        if (am < 6) a1 = *(const float4*)(pA0 + HW);
        uint4 w;
        w.x = pk(a0.x, a1.x); w.y = pk(a0.y, a1.y);
        w.z = pk(a0.z, a1.z); w.w = pk(a0.w, a1.w);
        *(uint4*)&apkw[aw] = w;
        // slice dy=1 -> regs (packed at iter 0)
        const float* p = pA0 + (size_t)WIN * HW;
        Ap0 = *(const float4*)p;
        if (am < 6) Ap1 = *(const float4*)(p + HW);
        PINF4(Ap0); PINF4(Ap1);
    }
    {   // window row y-6 -> ldsw[0]
        const int r0 = y - KD;
        if (r0 >= 0) {
            const float* p = in2_b + (size_t)r0 * NW;
            float4 Sv[5];
#pragma unroll
            for (int s = 0; s < 5; ++s)
                if (wadr[s] >= 0) Sv[s] = *(const float4*)&p[goff[s]];
#pragma unroll
            for (int s = 0; s < 5; ++s)
                if (wadr[s] >= 0) {
                    uint2 w; w.x = pk(Sv[s].x, Sv[s].y); w.y = pk(Sv[s].z, Sv[s].w);
                    *(uint2*)&ldsw[wadr[s]] = w;
                }
        }
    }
    BARRIER();

    for (int rr = 0; rr < WIN; ++rr) {
        const unsigned* cur  = ldsw + ((rr & 1) ? BUFW : 0);
        unsigned*       nxt  = ldsw + ((rr & 1) ? 0 : BUFW);
        const unsigned* acur = apkw + ((rr & 1) ? AFFPW : 0) + 4 * slot;
        unsigned*       anxt = apkw + ((rr & 1) ? 0 : AFFPW);
        const int  r  = y - KD + rr;
        const bool pv = (r >= 0) && (r < NH);          // block-uniform
        const int  rn = r + 1;
        const bool sv = (rr < WIN - 1) && (rn >= 0) && (rn < NH);
        const bool al = astg && (rr <= 10);            // load slice rr+2
        const bool ap = astg && (rr <= 11);            // pack slice rr+1

        // 1. issue aff loads for slice dy=rr+2 (consumed at iter rr+2)
        if (al) {
            const float* p = pA0 + (size_t)((rr + 2) * WIN) * HW;
            An0 = *(const float4*)p;
            An1 = make_float4(0.f, 0.f, 0.f, 0.f);
            if (am < 6) An1 = *(const float4*)(p + HW);
            PINF4(An0); PINF4(An1);
        }
        // 2. issue in2 staging loads for row rn
        float4 Sv[5];
        if (sv) {
            const float* p = in2_b + (size_t)rn * NW;
#pragma unroll
            for (int s = 0; s < 5; ++s)
                if (wadr[s] >= 0) Sv[s] = *(const float4*)&p[goff[s]];
#pragma unroll
            for (int s = 0; s < 5; ++s)
                PINF4(Sv[s]);
        }
        __builtin_amdgcn_sched_barrier(0);

        // 3. pass, two i-halves; W pinned in regs, A4 chunks double-buffered
        if (pv) {
#pragma unroll
            for (int h = 0; h < 2; ++h) {
                unsigned Wa[10], Wb[10];
                const unsigned* wpa = cur + wbase + (2*h + 0) * (16 * PITCHW);
                const unsigned* wpb = cur + wbase + (2*h + 1) * (16 * PITCHW);
                *(uint2*)&Wa[0] = *(const uint2*)&wpa[0];
                *(uint2*)&Wa[2] = *(const uint2*)&wpa[2];
                *(uint2*)&Wa[4] = *(const uint2*)&wpa[4];
                *(uint2*)&Wa[6] = *(const uint2*)&wpa[6];
                *(uint2*)&Wa[8] = *(const uint2*)&wpa[8];
                *(uint2*)&Wb[0] = *(const uint2*)&wpb[0];
                *(uint2*)&Wb[2] = *(const uint2*)&wpb[2];
                *(uint2*)&Wb[4] = *(const uint2*)&wpb[4];
                *(uint2*)&Wb[6] = *(const uint2*)&wpb[6];
                *(uint2*)&Wb[8] = *(const uint2*)&wpb[8];
                asm volatile("" : "+v"(Wa[0]), "+v"(Wa[1]), "+v"(Wa[2]),
                                  "+v"(Wa[3]), "+v"(Wa[4]), "+v"(Wa[5]),
                                  "+v"(Wa[6]), "+v"(Wa[7]), "+v"(Wa[8]),
                                  "+v"(Wa[9]));
                asm volatile("" : "+v"(Wb[0]), "+v"(Wb[1]), "+v"(Wb[2]),
                                  "+v"(Wb[3]), "+v"(Wb[4]), "+v"(Wb[5]),
                                  "+v"(Wb[6]), "+v"(Wb[7]), "+v"(Wb[8]),
                                  "+v"(Wb[9]));
                uint4 ac = *(const uint4*)&acur[0];
#pragma unroll
                for (int m = 0; m < 7; ++m) {
                    uint4 an;
                    if (m < 6) {
                        an = *(const uint4*)&acur[(m + 1) * 64];
                        PINU4(an);
                    }
                    {
                        const unsigned p1 = Wa[m + 1];
                        const unsigned p2 = Wa[m + 2];
                        const unsigned p3 = Wa[m + 3];
                        const unsigned s1 = (p1 >> 16) | (p2 << 16);
                        const unsigned s2 = (p2 >> 16) | (p3 << 16);
                        acc[2*h][0] = FDOT2(h2(ac.x), h2(p1), acc[2*h][0]);
                        acc[2*h][1] = FDOT2(h2(ac.y), h2(s1), acc[2*h][1]);
                        acc[2*h][2] = FDOT2(h2(ac.z), h2(p2), acc[2*h][2]);
                        acc[2*h][3] = FDOT2(h2(ac.w), h2(s2), acc[2*h][3]);
                    }
                    {
                        const unsigned p1 = Wb[m + 1];
                        const unsigned p2 = Wb[m + 2];
                        const unsigned p3 = Wb[m + 3];
                        const unsigned s1 = (p1 >> 16) | (p2 << 16);
                        const unsigned s2 = (p2 >> 16) | (p3 << 16);
                        acc[2*h+1][0] = FDOT2(h2(ac.x), h2(p1), acc[2*h+1][0]);
                        acc[2*h+1][1] = FDOT2(h2(ac.y), h2(s1), acc[2*h+1][1]);
                        acc[2*h+1][2] = FDOT2(h2(ac.z), h2(p2), acc[2*h+1][2]);
                        acc[2*h+1][3] = FDOT2(h2(ac.w), h2(s2), acc[2*h+1][3]);
                    }
                    if (m < 6) ac = an;
                }
            }
        }

        // 4. pack slice rr+1 (loaded last iter) into the other apk buffer
        if (ap) {
            uint4 w;
            w.x = pk(Ap0.x, Ap1.x); w.y = pk(Ap0.y, Ap1.y);
            w.z = pk(Ap0.z, Ap1.z); w.w = pk(Ap0.w, Ap1.w);
            *(uint4*)&anxt[aw] = w;
        }
        if (al) { Ap0 = An0; Ap1 = An1; }   // rotate the reg pipeline
        // 5. pack + write the staged in2 row
        if (sv) {
#pragma unroll
            for (int s = 0; s < 5; ++s)
                if (wadr[s] >= 0) {
                    uint2 w; w.x = pk(Sv[s].x, Sv[s].y); w.y = pk(Sv[s].z, Sv[s].w);
                    *(uint2*)&nxt[wadr[s]] = w;
                }
        }

        BARRIER();   // lgkmcnt(0) + s_barrier; vmcnt stays counted
    }

    float* ob = out + (((size_t)b * NC + cg) * NH + y) * NW + x0;
#pragma unroll
    for (int i = 0; i < 4; ++i) {
        *(float4*)&ob[(size_t)(16 * i) * HW] =
            make_float4(acc[i][0], acc[i][1], acc[i][2], acc[i][3]);
    }
}

extern "C" void kernel_launch(void* const* d_in, const int* in_sizes, int n_in,
                              void* d_out, int out_size, void* d_ws, size_t ws_size,
                              hipStream_t stream) {
    const float* aff = (const float*)d_in[0];   // [4,169,192,192] f32
    const float* in2 = (const float*)d_in[1];   // [4, 64,192,192] f32
    float* outp = (float*)d_out;                // [4, 64,192,192] f32
    dim3 grid(NB * NH, 3, 1);                   // (xcd|b|y, xb)
    dim3 block(NTH);
    hipLaunchKernelGGL(mxassemble, grid, block, 0, stream, aff, in2, outp);
}

// Round 7
// 256.049 us; speedup vs baseline: 1.0277x; 1.0277x over previous
//
#include <hip/hip_runtime.h>

// out[b,c,y,x] = sum_{dy,dx in [0,13)} aff[b, dy*13+dx, y, x] * in2_zp[b, c, y+dy-6, x+dx-6]
// B=4 C=64 H=W=192 D=169.
//
// Round 13: the self-inflicted wound found. VGPR history: (256,2)->104,
// (3,4)->84, (4,8)->56/60 == 512/max_waves. The backend targets the MAX of
// amdgpu_waves_per_eu; r11/r12's (4,8) told it to squeeze to 64 regs, and
// it "spills" LDS-sourced values by re-reading LDS -> the ds_read->dot2
// serialization we kept diagnosing. Working set ~115 regs needs budget 128:
//  * amdgpu_waves_per_eu(4, 4): min caps VGPR at 128 (hard), max forbids
//    squeeze-to-64. LDS (25088B -> 6 blocks) stays above the 4-block cap.
//  * aff A-chunk reads hoisted out of the h-loop: r12 re-read the same 7
//    b128 per half (acur independent of h). Now 7 reads into A[7] (28 regs,
//    fits new budget), used by both halves. Halves aff LDS traffic.
//  * everything else = r12: W pinned + batched per half, raw lgkm-only
//    barrier (aff global loads stay in flight), depth-2 aff reg pipeline,
//    pitch-42 window, Sv staging, grid (768,3) XCD swizzle, dot2 core.
// Numerics: aff fp16 rtz + in2 fp16 rtz, fp32 accum (= r11/r12, absmax .25-.5).

#define KD   6
#define WIN  13
#define ND   169
#define NB   4
#define NC   64
#define NH   192
#define NW   192
#define HW   (NH * NW)
#define XH   64            // x-tile width per block (3 tiles across W)
#define PITCHW 42          // window LDS row pitch in words (84 halves >= 80)
#define BUFW (NC * PITCHW) // 2688 words per window buffer
#define AFFPW 448          // 7*64 pair-words per packed aff slice
#define NTH  256           // 4 waves

typedef _Float16 half2v __attribute__((ext_vector_type(2)));

static __device__ __forceinline__ half2v h2(unsigned u) {
    return __builtin_bit_cast(half2v, u);
}
static __device__ __forceinline__ unsigned pk(float a, float b) {
    return __builtin_bit_cast(unsigned, __builtin_amdgcn_cvt_pkrtz(a, b));
}

#if __has_builtin(__builtin_amdgcn_fdot2)
#define FDOT2(a, b, c) __builtin_amdgcn_fdot2((a), (b), (c), false)
#else
static __device__ __forceinline__ float fdot2_fb(half2v a, half2v b, float c) {
    return fmaf((float)a.x, (float)b.x, fmaf((float)a.y, (float)b.y, c));
}
#define FDOT2(a, b, c) fdot2_fb((a), (b), (c))
#endif

// Raw barrier: LDS producer->consumer only needs lgkmcnt; do NOT drain
// vmcnt (keeps the depth-2 aff loads in flight across the barrier).
#define BARRIER() asm volatile("s_waitcnt lgkmcnt(0)\n\ts_barrier" ::: "memory")
#define PINF4(v) asm volatile("" : "+v"((v).x), "+v"((v).y), "+v"((v).z), "+v"((v).w))
#define PINU4(v) asm volatile("" : "+v"((v).x), "+v"((v).y), "+v"((v).z), "+v"((v).w))

__global__ __launch_bounds__(NTH)
__attribute__((amdgpu_waves_per_eu(4, 4)))
void mxassemble(const float* __restrict__ aff,
                const float* __restrict__ in2,
                float* __restrict__ out) {
    __shared__ unsigned ldsw[2 * BUFW];    // fp16 window rows, double buffered
    __shared__ unsigned apkw[2 * AFFPW];   // fp16 aff dx-pair slices, dbuf

    // Grid (768, 3): bx = (k<<3)|g. Per XCD g: k = b*24 + yl, yl fastest;
    // y = 24*g + yl -> each XCD owns a 24-row band per batch, rows L2-hot.
    const int bx = blockIdx.x;
    const int g  = bx & 7;
    const int k  = bx >> 3;                // 0..95
    const int b  = k / 24;
    const int yl = k - 24 * b;
    const int y  = 24 * g + yl;
    const int xb = blockIdx.y;             // x-tile 0..2
    const int X0 = xb * XH;

    const int t    = threadIdx.x;
    const int l    = t & 63;
    const int wv   = t >> 6;               // wave 0..3
    const int cg   = l & 15;               // channel group; c = cg + 16*i
    const int xs   = l >> 4;               // 0..3
    const int slot = wv * 4 + xs;          // 0..15
    const int x0   = X0 + slot * 4;

    // Window row layout: half j in [0,80) <-> global x = X0 - 8 + j.
    // Zero the 8-half OOB aprons once (xb=0: words 0..3; xb=2: words 36..39).
    if (xb != 1) {
        const int w0 = (xb == 0) ? 0 : 36;
        if (t < NC * 2) {
            const int c = t >> 1, qq = t & 1;
            *(uint2*)&ldsw[c * PITCHW + w0 + 2 * qq]        = make_uint2(0u, 0u);
            *(uint2*)&ldsw[BUFW + c * PITCHW + w0 + 2 * qq] = make_uint2(0u, 0u);
        }
    }

    // in2 staging slots: item s covers (c, q) = 4 floats; 64ch x 20 chunks
    // = 1280 = 256 threads x 5.
    int wadr[5], goff[5];
#pragma unroll
    for (int s = 0; s < 5; ++s) {
        const int ii = t + NTH * s;
        const int c  = ii / 20;
        const int q  = ii - 20 * c;
        const int xg = X0 - 8 + 4 * q;
        const bool ok = (xg >= 0) && (xg < NW);
        wadr[s] = ok ? (c * PITCHW + 2 * q) : -1;
        goff[s] = c * HW + xg;
    }

    // aff pair-staging mapping (t < 112): m = t>>4 in [0,7), xc = t&15.
    const int am  = t >> 4;
    const int axc = t & 15;
    const bool astg = (t < 112);
    const float* pA0 = aff + (size_t)b * ND * HW + (size_t)y * NW + X0
                           + 4 * axc + (size_t)(2 * am) * HW;
    const int aw = am * 64 + 4 * axc;

    float acc[4][4];
#pragma unroll
    for (int i = 0; i < 4; ++i)
#pragma unroll
        for (int j = 0; j < 4; ++j) acc[i][j] = 0.f;

    const float* in2_b = in2 + (size_t)b * NC * HW;
    const int wbase = cg * PITCHW + 2 * slot;

    // Depth-2 aff register pipeline: Ap = slice rr+1 (packed this iter),
    // An = slice rr+2 (loaded this iter).
    float4 Ap0 = make_float4(0.f, 0.f, 0.f, 0.f), Ap1 = Ap0;
    float4 An0 = Ap0, An1 = Ap0;

    // ---- prologue ----
    if (astg) {
        // slice dy=0 -> apk[0] immediately
        const float4 a0 = *(const float4*)pA0;
        float4 a1 = make_float4(0.f, 0.f, 0.f, 0.f);
        if (am < 6) a1 = *(const float4*)(pA0 + HW);
        uint4 w;
        w.x = pk(a0.x, a1.x); w.y = pk(a0.y, a1.y);
        w.z = pk(a0.z, a1.z); w.w = pk(a0.w, a1.w);
        *(uint4*)&apkw[aw] = w;
        // slice dy=1 -> regs (packed at iter 0)
        const float* p = pA0 + (size_t)WIN * HW;
        Ap0 = *(const float4*)p;
        if (am < 6) Ap1 = *(const float4*)(p + HW);
        PINF4(Ap0); PINF4(Ap1);
    }
    {   // window row y-6 -> ldsw[0]
        const int r0 = y - KD;
        if (r0 >= 0) {
            const float* p = in2_b + (size_t)r0 * NW;
            float4 Sv[5];
#pragma unroll
            for (int s = 0; s < 5; ++s)
                if (wadr[s] >= 0) Sv[s] = *(const float4*)&p[goff[s]];
#pragma unroll
            for (int s = 0; s < 5; ++s)
                if (wadr[s] >= 0) {
                    uint2 w; w.x = pk(Sv[s].x, Sv[s].y); w.y = pk(Sv[s].z, Sv[s].w);
                    *(uint2*)&ldsw[wadr[s]] = w;
                }
        }
    }
    BARRIER();

    for (int rr = 0; rr < WIN; ++rr) {
        const unsigned* cur  = ldsw + ((rr & 1) ? BUFW : 0);
        unsigned*       nxt  = ldsw + ((rr & 1) ? 0 : BUFW);
        const unsigned* acur = apkw + ((rr & 1) ? AFFPW : 0) + 4 * slot;
        unsigned*       anxt = apkw + ((rr & 1) ? 0 : AFFPW);
        const int  r  = y - KD + rr;
        const bool pv = (r >= 0) && (r < NH);          // block-uniform
        const int  rn = r + 1;
        const bool sv = (rr < WIN - 1) && (rn >= 0) && (rn < NH);
        const bool al = astg && (rr <= 10);            // load slice rr+2
        const bool ap = astg && (rr <= 11);            // pack slice rr+1

        // 1. issue aff loads for slice dy=rr+2 (consumed at iter rr+2)
        if (al) {
            const float* p = pA0 + (size_t)((rr + 2) * WIN) * HW;
            An0 = *(const float4*)p;
            An1 = make_float4(0.f, 0.f, 0.f, 0.f);
            if (am < 6) An1 = *(const float4*)(p + HW);
            PINF4(An0); PINF4(An1);
        }
        // 2. issue in2 staging loads for row rn
        float4 Sv[5];
        if (sv) {
            const float* p = in2_b + (size_t)rn * NW;
#pragma unroll
            for (int s = 0; s < 5; ++s)
                if (wadr[s] >= 0) Sv[s] = *(const float4*)&p[goff[s]];
#pragma unroll
            for (int s = 0; s < 5; ++s)
                PINF4(Sv[s]);
        }
        __builtin_amdgcn_sched_barrier(0);

        // 3. pass: A[7] hoisted (shared by both halves), W pinned per half
        if (pv) {
            uint4 A[7];
#pragma unroll
            for (int m = 0; m < 7; ++m) A[m] = *(const uint4*)&acur[m * 64];
#pragma unroll
            for (int m = 0; m < 7; ++m) PINU4(A[m]);
#pragma unroll
            for (int h = 0; h < 2; ++h) {
                unsigned Wa[10], Wb[10];
                const unsigned* wpa = cur + wbase + (2*h + 0) * (16 * PITCHW);
                const unsigned* wpb = cur + wbase + (2*h + 1) * (16 * PITCHW);
                *(uint2*)&Wa[0] = *(const uint2*)&wpa[0];
                *(uint2*)&Wa[2] = *(const uint2*)&wpa[2];
                *(uint2*)&Wa[4] = *(const uint2*)&wpa[4];
                *(uint2*)&Wa[6] = *(const uint2*)&wpa[6];
                *(uint2*)&Wa[8] = *(const uint2*)&wpa[8];
                *(uint2*)&Wb[0] = *(const uint2*)&wpb[0];
                *(uint2*)&Wb[2] = *(const uint2*)&wpb[2];
                *(uint2*)&Wb[4] = *(const uint2*)&wpb[4];
                *(uint2*)&Wb[6] = *(const uint2*)&wpb[6];
                *(uint2*)&Wb[8] = *(const uint2*)&wpb[8];
                asm volatile("" : "+v"(Wa[0]), "+v"(Wa[1]), "+v"(Wa[2]),
                                  "+v"(Wa[3]), "+v"(Wa[4]), "+v"(Wa[5]),
                                  "+v"(Wa[6]), "+v"(Wa[7]), "+v"(Wa[8]),
                                  "+v"(Wa[9]));
                asm volatile("" : "+v"(Wb[0]), "+v"(Wb[1]), "+v"(Wb[2]),
                                  "+v"(Wb[3]), "+v"(Wb[4]), "+v"(Wb[5]),
                                  "+v"(Wb[6]), "+v"(Wb[7]), "+v"(Wb[8]),
                                  "+v"(Wb[9]));
#pragma unroll
                for (int m = 0; m < 7; ++m) {
                    {
                        const unsigned p1 = Wa[m + 1];
                        const unsigned p2 = Wa[m + 2];
                        const unsigned p3 = Wa[m + 3];
                        const unsigned s1 = (p1 >> 16) | (p2 << 16);
                        const unsigned s2 = (p2 >> 16) | (p3 << 16);
                        acc[2*h][0] = FDOT2(h2(A[m].x), h2(p1), acc[2*h][0]);
                        acc[2*h][1] = FDOT2(h2(A[m].y), h2(s1), acc[2*h][1]);
                        acc[2*h][2] = FDOT2(h2(A[m].z), h2(p2), acc[2*h][2]);
                        acc[2*h][3] = FDOT2(h2(A[m].w), h2(s2), acc[2*h][3]);
                    }
                    {
                        const unsigned p1 = Wb[m + 1];
                        const unsigned p2 = Wb[m + 2];
                        const unsigned p3 = Wb[m + 3];
                        const unsigned s1 = (p1 >> 16) | (p2 << 16);
                        const unsigned s2 = (p2 >> 16) | (p3 << 16);
                        acc[2*h+1][0] = FDOT2(h2(A[m].x), h2(p1), acc[2*h+1][0]);
                        acc[2*h+1][1] = FDOT2(h2(A[m].y), h2(s1), acc[2*h+1][1]);
                        acc[2*h+1][2] = FDOT2(h2(A[m].z), h2(p2), acc[2*h+1][2]);
                        acc[2*h+1][3] = FDOT2(h2(A[m].w), h2(s2), acc[2*h+1][3]);
                    }
                }
            }
        }

        // 4. pack slice rr+1 (loaded last iter) into the other apk buffer
        if (ap) {
            uint4 w;
            w.x = pk(Ap0.x, Ap1.x); w.y = pk(Ap0.y, Ap1.y);
            w.z = pk(Ap0.z, Ap1.z); w.w = pk(Ap0.w, Ap1.w);
            *(uint4*)&anxt[aw] = w;
        }
        if (al) { Ap0 = An0; Ap1 = An1; }   // rotate the reg pipeline
        // 5. pack + write the staged in2 row
        if (sv) {
#pragma unroll
            for (int s = 0; s < 5; ++s)
                if (wadr[s] >= 0) {
                    uint2 w; w.x = pk(Sv[s].x, Sv[s].y); w.y = pk(Sv[s].z, Sv[s].w);
                    *(uint2*)&nxt[wadr[s]] = w;
                }
        }

        BARRIER();   // lgkmcnt(0) + s_barrier; vmcnt stays counted
    }

    float* ob = out + (((size_t)b * NC + cg) * NH + y) * NW + x0;
#pragma unroll
    for (int i = 0; i < 4; ++i) {
        *(float4*)&ob[(size_t)(16 * i) * HW] =
            make_float4(acc[i][0], acc[i][1], acc[i][2], acc[i][3]);
    }
}

extern "C" void kernel_launch(void* const* d_in, const int* in_sizes, int n_in,
                              void* d_out, int out_size, void* d_ws, size_t ws_size,
                              hipStream_t stream) {
    const float* aff = (const float*)d_in[0];   // [4,169,192,192] f32
    const float* in2 = (const float*)d_in[1];   // [4, 64,192,192] f32
    float* outp = (float*)d_out;                // [4, 64,192,192] f32
    dim3 grid(NB * NH, 3, 1);                   // (xcd|b|y, xb)
    dim3 block(NTH);
    hipLaunchKernelGGL(mxassemble, grid, block, 0, stream, aff, in2, outp);
}